// Round 1
// baseline (5540.140 us; speedup 1.0000x reference)
//
#include <hip/hip_runtime.h>
#include <hip/hip_bf16.h>

#define BATCH 1024
#define TSEQ  2048
#define DIN   15
#define DINP  16   // padded x row in LDS
#define HID   64
#define NG    256  // 4*HID gates
#define CHUNK 64   // timesteps of x staged in LDS per load
#define NCLS  4

__device__ __forceinline__ float rcp_f(float x) { return __builtin_amdgcn_rcpf(x); }
__device__ __forceinline__ float sigm_f(float z) { return rcp_f(1.0f + __expf(-z)); }
__device__ __forceinline__ float tanh_f(float z) { return 1.0f - 2.0f * rcp_f(1.0f + __expf(2.0f * z)); }

// One block per batch element. Thread g owns gate g (0..255) of BOTH layers,
// weight rows register-resident (15+64+64+64 = 207 VGPRs of weights).
// Gate order (PyTorch): [0,64)=i  [64,128)=f  [128,192)=g  [192,256)=o.
// Each 64-gate chunk == one wave -> activation select is wave-uniform.
__global__ __launch_bounds__(NG, 2)
void lstm2_fused(const float* __restrict__ x,
                 const float* __restrict__ wih0, const float* __restrict__ whh0,
                 const float* __restrict__ bih0, const float* __restrict__ bhh0,
                 const float* __restrict__ wih1, const float* __restrict__ whh1,
                 const float* __restrict__ bih1, const float* __restrict__ bhh1,
                 const float* __restrict__ fcw,  const float* __restrict__ fcb,
                 float* __restrict__ out)
{
    const int b = blockIdx.x;
    const int g = threadIdx.x;

    // ---- register-resident weight rows -------------------------------------
    float rwi0[DINP];      // w_ih0 row g (padded with 0)
    float rw0[HID];        // w_hh0 row g
    float rw1[2 * HID];    // [w_ih1 row g | w_hh1 row g]  (matches [h0|h1] concat)
    {
        const float* p = wih0 + g * DIN;
        #pragma unroll
        for (int d = 0; d < DIN; ++d) rwi0[d] = p[d];
        rwi0[DIN] = 0.0f;

        const float4* q0 = (const float4*)(whh0 + g * HID);
        #pragma unroll
        for (int k = 0; k < HID / 4; ++k) ((float4*)rw0)[k] = q0[k];

        const float4* q1 = (const float4*)(wih1 + g * HID);
        #pragma unroll
        for (int k = 0; k < HID / 4; ++k) ((float4*)rw1)[k] = q1[k];

        const float4* q2 = (const float4*)(whh1 + g * HID);
        #pragma unroll
        for (int k = 0; k < HID / 4; ++k) ((float4*)(rw1 + HID))[k] = q2[k];
    }
    const float pb0 = bih0[g] + bhh0[g];
    const float pb1 = bih1[g] + bhh1[g];

    // ---- LDS state ----------------------------------------------------------
    __shared__ __align__(16) float shc[2 * HID];      // [h0 | h1]
    __shared__ __align__(16) float sg0[NG];           // layer-0 activated gates
    __shared__ __align__(16) float sg1[NG];           // layer-1 activated gates
    __shared__ __align__(16) float sx[CHUNK * DINP];  // x chunk, padded rows

    if (g < 2 * HID) shc[g] = 0.0f;   // h0=h1=0

    float c0 = 0.0f, c1 = 0.0f;       // cell state (meaningful for g < 64)

    const float* xb = x + (size_t)b * TSEQ * DIN;

    for (int t = 0; t < TSEQ; ++t) {
        // ---- stage next 64 timesteps of x (all prior sx reads happened
        // before the previous step's barriers, so writing is safe here) ----
        if ((t & (CHUNK - 1)) == 0) {
            #pragma unroll
            for (int idx = g; idx < CHUNK * DIN; idx += NG) {
                int s = idx / DIN;
                int d = idx - s * DIN;
                sx[s * DINP + d] = xb[(size_t)t * DIN + idx];
            }
            if (g < CHUNK) sx[g * DINP + DIN] = 0.0f;  // zero pad lane
            __syncthreads();
        }

        const float4* xs4 = (const float4*)(sx + (t & (CHUNK - 1)) * DINP);

        // ---- layer 0 gate g: pb0 + x_t . wih0[g] + h0 . whh0[g] ----
        float a0 = pb0, a1 = 0.0f, a2 = 0.0f, a3 = 0.0f;
        #pragma unroll
        for (int k = 0; k < DINP / 4; ++k) {
            float4 v = xs4[k];
            a0 += v.x * rwi0[4 * k + 0];
            a1 += v.y * rwi0[4 * k + 1];
            a2 += v.z * rwi0[4 * k + 2];
            a3 += v.w * rwi0[4 * k + 3];
        }
        const float4* h04 = (const float4*)shc;  // h0 = shc[0:64]
        #pragma unroll
        for (int k = 0; k < HID / 4; ++k) {
            float4 v = h04[k];
            a0 += v.x * rw0[4 * k + 0];
            a1 += v.y * rw0[4 * k + 1];
            a2 += v.z * rw0[4 * k + 2];
            a3 += v.w * rw0[4 * k + 3];
        }
        float z0 = (a0 + a1) + (a2 + a3);
        sg0[g] = ((g >> 6) == 2) ? tanh_f(z0) : sigm_f(z0);
        __syncthreads();                                   // b1

        if (g < HID) {  // wave 0 updates c0, h0
            float iv = sg0[g], fv = sg0[HID + g], gv = sg0[2 * HID + g], ov = sg0[3 * HID + g];
            c0 = fv * c0 + iv * gv;
            shc[g] = ov * tanh_f(c0);
        }
        __syncthreads();                                   // b2

        // ---- layer 1 gate g: pb1 + [h0|h1] . [wih1|whh1][g] ----
        float d0 = pb1, d1 = 0.0f, d2 = 0.0f, d3 = 0.0f;
        const float4* hc4 = (const float4*)shc;            // [h0|h1] = shc[0:128]
        #pragma unroll
        for (int k = 0; k < (2 * HID) / 4; ++k) {
            float4 v = hc4[k];
            d0 += v.x * rw1[4 * k + 0];
            d1 += v.y * rw1[4 * k + 1];
            d2 += v.z * rw1[4 * k + 2];
            d3 += v.w * rw1[4 * k + 3];
        }
        float z1 = (d0 + d1) + (d2 + d3);
        sg1[g] = ((g >> 6) == 2) ? tanh_f(z1) : sigm_f(z1);
        __syncthreads();                                   // b3

        if (g < HID) {  // wave 0 updates c1, h1.  No 4th barrier needed:
            // readers of shc[64:128] only touch it after b2 of step t+1,
            // which this wave reaches only after completing these writes.
            float iv = sg1[g], fv = sg1[HID + g], gv = sg1[2 * HID + g], ov = sg1[3 * HID + g];
            c1 = fv * c1 + iv * gv;
            shc[HID + g] = ov * tanh_f(c1);
        }
    }
    __syncthreads();

    // ---- FC + softmax on h1 (= shc[64:128]) --------------------------------
    if (g < NCLS) {
        float acc = fcb[g];
        const float* w = fcw + g * HID;
        #pragma unroll
        for (int k = 0; k < HID; ++k) acc += shc[HID + k] * w[k];
        sg0[g] = acc;
    }
    __syncthreads();
    if (g == 0) {
        float l0 = sg0[0], l1 = sg0[1], l2 = sg0[2], l3 = sg0[3];
        float m = fmaxf(fmaxf(l0, l1), fmaxf(l2, l3));
        float e0 = __expf(l0 - m), e1 = __expf(l1 - m);
        float e2 = __expf(l2 - m), e3 = __expf(l3 - m);
        float inv = rcp_f(e0 + e1 + e2 + e3);
        out[b * NCLS + 0] = e0 * inv;
        out[b * NCLS + 1] = e1 * inv;
        out[b * NCLS + 2] = e2 * inv;
        out[b * NCLS + 3] = e3 * inv;
    }
}

extern "C" void kernel_launch(void* const* d_in, const int* in_sizes, int n_in,
                              void* d_out, int out_size, void* d_ws, size_t ws_size,
                              hipStream_t stream) {
    const float* x    = (const float*)d_in[0];
    const float* wih0 = (const float*)d_in[1];
    const float* whh0 = (const float*)d_in[2];
    const float* bih0 = (const float*)d_in[3];
    const float* bhh0 = (const float*)d_in[4];
    const float* wih1 = (const float*)d_in[5];
    const float* whh1 = (const float*)d_in[6];
    const float* bih1 = (const float*)d_in[7];
    const float* bhh1 = (const float*)d_in[8];
    const float* fcw  = (const float*)d_in[9];
    const float* fcb  = (const float*)d_in[10];
    float* out = (float*)d_out;

    lstm2_fused<<<BATCH, NG, 0, stream>>>(x, wih0, whh0, bih0, bhh0,
                                          wih1, whh1, bih1, bhh1,
                                          fcw, fcb, out);
}